// Round 8
// baseline (173.356 us; speedup 1.0000x reference)
//
#include <hip/hip_runtime.h>
#include <hip/hip_fp16.h>
#include <math.h>

#define NSAMP 256

#if defined(__has_builtin)
#  if __has_builtin(__builtin_amdgcn_fdot2)
#    define HAVE_FDOT2 1
#  endif
#endif

typedef _Float16 h2 __attribute__((ext_vector_type(2)));

// ---------- pre-pass 1: transpose F [32ch][32768vox] -> Ft [vox][32ch] ----------
__global__ __launch_bounds__(256) void transpose_F(
    const float* __restrict__ Fg, float* __restrict__ Ft)
{
    const int j = blockIdx.x * 256 + threadIdx.x;   // voxel id 0..32767
    float4 o[8];
    #pragma unroll
    for (int q = 0; q < 8; ++q) {
        o[q].x = Fg[(size_t)(4*q+0)*32768 + j];
        o[q].y = Fg[(size_t)(4*q+1)*32768 + j];
        o[q].z = Fg[(size_t)(4*q+2)*32768 + j];
        o[q].w = Fg[(size_t)(4*q+3)*32768 + j];
    }
    float4* dst = (float4*)(Ft + (size_t)j * 32);
    #pragma unroll
    for (int q = 0; q < 8; ++q) dst[q] = o[q];
}

// ---------- pre-pass 2: pack layer-1 weights as half2 pairs over k ----------
// wdh[k2*64+j] = (Wd1[2k2][j], Wd1[2k2+1][j]);  same for Wc1 (first 32 rows).
__global__ __launch_bounds__(256) void pack_weights(
    const float* __restrict__ Wd1, const float* __restrict__ Wc1,
    __half2* __restrict__ wdh, __half2* __restrict__ wch)
{
    const int idx = blockIdx.x * 256 + threadIdx.x;  // 0..1023
    if (idx < 1024) {
        const int k2 = idx >> 6, j = idx & 63;
        wdh[idx] = __floats2half2_rn(Wd1[(2*k2)*64 + j], Wd1[(2*k2+1)*64 + j]);
        wch[idx] = __floats2half2_rn(Wc1[(2*k2)*64 + j], Wc1[(2*k2+1)*64 + j]);
    }
}

// ---------- main fused kernel ----------
// Round-8: waves_per_eu max 4 -> 7. The max=4 was padding descriptor
// occupancy to 4 waves/EU (50% cap; 27% observed) while VGPR=68 would
// allow ~7. min stays 2 so the allocator keeps its 256-reg budget (no
// re-spill). Single change vs round 7 for clean attribution.
template<bool USE_T>
__global__ __launch_bounds__(256) __attribute__((amdgpu_waves_per_eu(2, 7)))
void nerf_fused(
    const float* __restrict__ rays_o, const float* __restrict__ rays_d,
    const float* __restrict__ G1, const float* __restrict__ Fg,
    const float* __restrict__ Wd1, const float* __restrict__ bd1,
    const float* __restrict__ Wd2, const float* __restrict__ bd2,
    const float* __restrict__ Wc1, const float* __restrict__ bc1,
    const float* __restrict__ Wc2, const float* __restrict__ bc2,
    const float* __restrict__ Ft,
    const __half2* __restrict__ wdh, const __half2* __restrict__ wch,
    float* __restrict__ out)
{
    const float RADIUS = 1.3f;
    const float STEP = 0.0176f;

    const int b    = blockIdx.x;
    const int tid  = threadIdx.x;
    const int lane = tid & 63;
    const int wv   = tid >> 6;

    __shared__ float s_wtot[4];
    __shared__ float s_red[4][4];

    // ---- ray setup ----
    const float ox = rays_o[b*3+0], oy = rays_o[b*3+1], oz = rays_o[b*3+2];
    const float rdx = rays_d[b*3+0], rdy = rays_d[b*3+1], rdz = rays_d[b*3+2];
    const float rn  = sqrtf(rdx*rdx + rdy*rdy + rdz*rdz);
    const float dxn = rdx/rn, dyn = rdy/rn, dzn = rdz/rn;

    // ---- cube intersection ----
    float sd, inv, t1, t2, tmin, tmax;
    sd = (fabsf(dxn) < 1e-9f) ? 1e-9f : dxn; inv = 1.0f/sd;
    t1 = (-RADIUS - ox)*inv; t2 = (RADIUS - ox)*inv;
    tmin = fminf(t1,t2); tmax = fmaxf(t1,t2);
    sd = (fabsf(dyn) < 1e-9f) ? 1e-9f : dyn; inv = 1.0f/sd;
    t1 = (-RADIUS - oy)*inv; t2 = (RADIUS - oy)*inv;
    tmin = fmaxf(tmin, fminf(t1,t2)); tmax = fminf(tmax, fmaxf(t1,t2));
    sd = (fabsf(dzn) < 1e-9f) ? 1e-9f : dzn; inv = 1.0f/sd;
    t1 = (-RADIUS - oz)*inv; t2 = (RADIUS - oz)*inv;
    tmin = fmaxf(tmin, fminf(t1,t2)); tmax = fminf(tmax, fmaxf(t1,t2));

    const float tnear = fmaxf(tmin, 0.0f);
    const bool  hit   = tmax > tnear;
    const float t     = tnear + STEP * (float)tid;
    const bool  mask  = (t < tmax) && hit;

    float sigma = 0.0f, rr = 0.0f, rg = 0.0f, rb = 0.0f;

    // ---- wave-coherent early-out ----
    if (__any(mask)) {
        // ---- sample position, normalized to [-1,1] ----
        const float invR = 1.0f / RADIUS;
        const float px = (ox + t*dxn) * invR;
        const float py = (oy + t*dyn) * invR;
        const float pz = (oz + t*dzn) * invR;

        // ---- trilinear G1 (C=3, 128^3) ----
        float cox = fminf(fmaxf((px+1.0f)*0.5f*127.0f, 0.0f), 127.0f);
        float coy = fminf(fmaxf((py+1.0f)*0.5f*127.0f, 0.0f), 127.0f);
        float coz = fminf(fmaxf((pz+1.0f)*0.5f*127.0f, 0.0f), 127.0f);
        int x0 = (int)floorf(cox); float fx = cox - (float)x0; int x1 = min(x0+1, 127);
        int y0 = (int)floorf(coy); float fy = coy - (float)y0; int y1 = min(y0+1, 127);
        int z0 = (int)floorf(coz); float fz = coz - (float)z0; int z1 = min(z0+1, 127);

        {
            const float wx0 = 1.0f-fx, wx1 = fx;
            const float wy0 = 1.0f-fy, wy1 = fy;
            const float wz0 = 1.0f-fz, wz1 = fz;
            const float w000 = wx0*wy0*wz0, w100 = wx1*wy0*wz0;
            const float w010 = wx0*wy1*wz0, w110 = wx1*wy1*wz0;
            const float w001 = wx0*wy0*wz1, w101 = wx1*wy0*wz1;
            const float w011 = wx0*wy1*wz1, w111 = wx1*wy1*wz1;
            const int i000 = (z0*128 + y0)*128 + x0;
            const int dxo = x1 - x0;
            const int dyo = (y1 - y0)*128;
            const int dzo = (z1 - z0)*16384;
            const int i100 = i000 + dxo,       i010 = i000 + dyo;
            const int i110 = i000 + dyo + dxo, i001 = i000 + dzo;
            const int i101 = i000 + dzo + dxo, i011 = i000 + dzo + dyo;
            const int i111 = i000 + dzo + dyo + dxo;

            float g[3];
            #pragma unroll
            for (int c = 0; c < 3; ++c) {
                const float* gp = G1 + (size_t)c * 2097152;
                g[c] = w000*gp[i000] + w100*gp[i100] + w010*gp[i010] + w110*gp[i110]
                     + w001*gp[i001] + w101*gp[i101] + w011*gp[i011] + w111*gp[i111];
            }

            // ---- F coords from g ----
            cox = fminf(fmaxf((g[0]+1.0f)*0.5f*31.0f, 0.0f), 31.0f);
            coy = fminf(fmaxf((g[1]+1.0f)*0.5f*31.0f, 0.0f), 31.0f);
            coz = fminf(fmaxf((g[2]+1.0f)*0.5f*31.0f, 0.0f), 31.0f);
            x0 = (int)floorf(cox); fx = cox - (float)x0; x1 = min(x0+1, 31);
            y0 = (int)floorf(coy); fy = coy - (float)y0; y1 = min(y0+1, 31);
            z0 = (int)floorf(coz); fz = coz - (float)z0; z1 = min(z0+1, 31);
        }

        // ---- trilinear F (C=32), corner-at-a-time ----
        float feats[32];
        #pragma unroll
        for (int c = 0; c < 32; ++c) feats[c] = 0.0f;
        {
            const float wx0 = 1.0f-fx, wx1 = fx;
            const float wy0 = 1.0f-fy, wy1 = fy;
            const float wz0 = 1.0f-fz, wz1 = fz;
            const int j000 = (z0*32 + y0)*32 + x0;
            const int dxo = x1 - x0;
            const int dyo = (y1 - y0)*32;
            const int dzo = (z1 - z0)*1024;

            const int   jidx[8] = { j000,           j000+dxo,
                                    j000+dyo,       j000+dyo+dxo,
                                    j000+dzo,       j000+dzo+dxo,
                                    j000+dzo+dyo,   j000+dzo+dyo+dxo };
            const float jwt[8]  = { wx0*wy0*wz0, wx1*wy0*wz0,
                                    wx0*wy1*wz0, wx1*wy1*wz0,
                                    wx0*wy0*wz1, wx1*wy0*wz1,
                                    wx0*wy1*wz1, wx1*wy1*wz1 };

            if (USE_T) {
                #pragma unroll
                for (int corner = 0; corner < 8; ++corner) {
                    const float4* fp = (const float4*)(Ft + (size_t)jidx[corner] * 32);
                    const float w = jwt[corner];
                    #pragma unroll
                    for (int q = 0; q < 8; ++q) {
                        const float4 v = fp[q];
                        feats[4*q+0] += w * v.x;
                        feats[4*q+1] += w * v.y;
                        feats[4*q+2] += w * v.z;
                        feats[4*q+3] += w * v.w;
                    }
                }
            } else {
                #pragma unroll
                for (int corner = 0; corner < 8; ++corner) {
                    const float w = jwt[corner];
                    const int  j  = jidx[corner];
                    #pragma unroll
                    for (int c = 0; c < 32; ++c)
                        feats[c] += w * Fg[(size_t)c * 32768 + j];
                }
            }
        }

        // ---- fused MLPs ----
        sigma = bd2[0];
        float cr = 0.0f, cg = 0.0f, cb = 0.0f;

#ifdef HAVE_FDOT2
        h2 fh[16];
        #pragma unroll
        for (int i = 0; i < 16; ++i) {
            __half2 ph = __floats2half2_rn(feats[2*i], feats[2*i+1]);
            fh[i] = *reinterpret_cast<h2*>(&ph);
        }
        for (int j0 = 0; j0 < 64; j0 += 8) {
            float ad[8], ac[8];
            #pragma unroll
            for (int jj = 0; jj < 8; ++jj) {
                ad[jj] = bd1[j0+jj];
                ac[jj] = bc1[j0+jj] + dxn*Wc1[32*64 + j0 + jj]
                                    + dyn*Wc1[33*64 + j0 + jj]
                                    + dzn*Wc1[34*64 + j0 + jj];
            }
            #pragma unroll
            for (int k2 = 0; k2 < 16; ++k2) {
                const h2 fv = fh[k2];
                #pragma unroll
                for (int jj = 0; jj < 8; ++jj) {
                    __half2 wd = wdh[k2*64 + j0 + jj];
                    __half2 wc = wch[k2*64 + j0 + jj];
                    ad[jj] = __builtin_amdgcn_fdot2(fv, *reinterpret_cast<h2*>(&wd), ad[jj], false);
                    ac[jj] = __builtin_amdgcn_fdot2(fv, *reinterpret_cast<h2*>(&wc), ac[jj], false);
                }
            }
            #pragma unroll
            for (int jj = 0; jj < 8; ++jj) {
                sigma += fmaxf(ad[jj], 0.0f) * Wd2[j0+jj];
                const float hc = fmaxf(ac[jj], 0.0f);
                cr += hc * Wc2[(j0+jj)*3 + 0];
                cg += hc * Wc2[(j0+jj)*3 + 1];
                cb += hc * Wc2[(j0+jj)*3 + 2];
            }
        }
#else
        for (int j0 = 0; j0 < 64; j0 += 8) {
            float ad[8], ac[8];
            #pragma unroll
            for (int jj = 0; jj < 8; ++jj) {
                ad[jj] = bd1[j0+jj];
                ac[jj] = bc1[j0+jj] + dxn*Wc1[32*64 + j0 + jj]
                                    + dyn*Wc1[33*64 + j0 + jj]
                                    + dzn*Wc1[34*64 + j0 + jj];
            }
            #pragma unroll
            for (int k = 0; k < 32; ++k) {
                const float fv = feats[k];
                #pragma unroll
                for (int jj = 0; jj < 8; ++jj) {
                    ad[jj] += fv * Wd1[k*64 + j0 + jj];
                    ac[jj] += fv * Wc1[k*64 + j0 + jj];
                }
            }
            #pragma unroll
            for (int jj = 0; jj < 8; ++jj) {
                sigma += fmaxf(ad[jj], 0.0f) * Wd2[j0+jj];
                const float hc = fmaxf(ac[jj], 0.0f);
                cr += hc * Wc2[(j0+jj)*3 + 0];
                cg += hc * Wc2[(j0+jj)*3 + 1];
                cb += hc * Wc2[(j0+jj)*3 + 2];
            }
        }
#endif
        cr += bc2[0]; cg += bc2[1]; cb += bc2[2];
        rr = 1.0f/(1.0f + expf(-cr));
        rg = 1.0f/(1.0f + expf(-cg));
        rb = 1.0f/(1.0f + expf(-cb));

        // per-lane masking
        sigma = mask ? sigma : 0.0f;
        rr = mask ? rr : 0.0f;
        rg = mask ? rg : 0.0f;
        rb = mask ? rb : 0.0f;
    }

    // ---- alpha, exclusive product scan (T_excl), weights ----
    const float alpha = 1.0f - expf(-fmaxf(sigma, 0.0f) * STEP);
    float p = 1.0f - alpha + 1e-10f;

    float scan = p;
    #pragma unroll
    for (int off = 1; off < 64; off <<= 1) {
        const float n = __shfl_up(scan, off, 64);
        if (lane >= off) scan *= n;
    }
    if (lane == 63) s_wtot[wv] = scan;
    __syncthreads();

    float pre = 1.0f;
    #pragma unroll
    for (int q = 0; q < 4; ++q) if (q < wv) pre *= s_wtot[q];
    float excl = __shfl_up(scan, 1, 64);
    if (lane == 0) excl = 1.0f;
    const float Texcl = pre * excl;

    const float w = alpha * Texcl;
    float sw  = w;
    float swr = w * rr, swg = w * rg, swb = w * rb;

    // ---- block reduction ----
    #pragma unroll
    for (int off = 32; off > 0; off >>= 1) {
        sw  += __shfl_down(sw,  off, 64);
        swr += __shfl_down(swr, off, 64);
        swg += __shfl_down(swg, off, 64);
        swb += __shfl_down(swb, off, 64);
    }
    if (lane == 0) {
        s_red[wv][0] = sw;  s_red[wv][1] = swr;
        s_red[wv][2] = swg; s_red[wv][3] = swb;
    }
    __syncthreads();
    if (tid == 0) {
        float W = 0.0f, R = 0.0f, Gc = 0.0f, Bc = 0.0f;
        #pragma unroll
        for (int q = 0; q < 4; ++q) {
            W  += s_red[q][0]; R  += s_red[q][1];
            Gc += s_red[q][2]; Bc += s_red[q][3];
        }
        const float bg = 1.0f - W;
        out[b*3+0] = R  + bg;
        out[b*3+1] = Gc + bg;
        out[b*3+2] = Bc + bg;
    }
}

extern "C" void kernel_launch(void* const* d_in, const int* in_sizes, int n_in,
                              void* d_out, int out_size, void* d_ws, size_t ws_size,
                              hipStream_t stream) {
    const float* rays_o = (const float*)d_in[0];
    const float* rays_d = (const float*)d_in[1];
    const float* G1     = (const float*)d_in[2];
    const float* Fg     = (const float*)d_in[3];
    const float* Wd1    = (const float*)d_in[4];
    const float* bd1    = (const float*)d_in[5];
    const float* Wd2    = (const float*)d_in[6];
    const float* bd2    = (const float*)d_in[7];
    const float* Wc1    = (const float*)d_in[8];
    const float* bc1    = (const float*)d_in[9];
    const float* Wc2    = (const float*)d_in[10];
    const float* bc2    = (const float*)d_in[11];
    float* out = (float*)d_out;

    const int B = in_sizes[0] / 3;   // 2048 rays
    const size_t ft_bytes = (size_t)32768 * 32 * sizeof(float);   // 4 MB
    const size_t pk_bytes = (size_t)1024 * sizeof(__half2);       // 4 KB each

    if (ws_size >= ft_bytes + 2*pk_bytes) {
        float*   Ft  = (float*)d_ws;
        __half2* wdh = (__half2*)((char*)d_ws + ft_bytes);
        __half2* wch = (__half2*)((char*)d_ws + ft_bytes + pk_bytes);
        transpose_F<<<dim3(128), dim3(256), 0, stream>>>(Fg, Ft);
        pack_weights<<<dim3(4), dim3(256), 0, stream>>>(Wd1, Wc1, wdh, wch);
        nerf_fused<true><<<dim3(B), dim3(NSAMP), 0, stream>>>(
            rays_o, rays_d, G1, Fg, Wd1, bd1, Wd2, bd2, Wc1, bc1, Wc2, bc2,
            Ft, wdh, wch, out);
    } else {
        __half2* wdh = (__half2*)d_ws;
        __half2* wch = wdh + 1024;
        if (ws_size >= 2*pk_bytes)
            pack_weights<<<dim3(4), dim3(256), 0, stream>>>(Wd1, Wc1, wdh, wch);
        nerf_fused<false><<<dim3(B), dim3(NSAMP), 0, stream>>>(
            rays_o, rays_d, G1, Fg, Wd1, bd1, Wd2, bd2, Wc1, bc1, Wc2, bc2,
            Fg, wdh, wch, out);
    }
}

// Round 9
// 144.940 us; speedup vs baseline: 1.1961x; 1.1961x over previous
//
#include <hip/hip_runtime.h>
#include <hip/hip_fp16.h>
#include <math.h>

#define NSAMP 256

typedef _Float16 f16;
typedef _Float16 f16x8 __attribute__((ext_vector_type(8)));
typedef float    f32x4 __attribute__((ext_vector_type(4)));

// ---------- pre-pass 1: transpose F [32ch][32768vox] -> Ft [vox][32ch] ----------
__global__ __launch_bounds__(256) void transpose_F(
    const float* __restrict__ Fg, float* __restrict__ Ft)
{
    const int j = blockIdx.x * 256 + threadIdx.x;   // voxel id 0..32767
    float4 o[8];
    #pragma unroll
    for (int q = 0; q < 8; ++q) {
        o[q].x = Fg[(size_t)(4*q+0)*32768 + j];
        o[q].y = Fg[(size_t)(4*q+1)*32768 + j];
        o[q].z = Fg[(size_t)(4*q+2)*32768 + j];
        o[q].w = Fg[(size_t)(4*q+3)*32768 + j];
    }
    float4* dst = (float4*)(Ft + (size_t)j * 32);
    #pragma unroll
    for (int q = 0; q < 8; ++q) dst[q] = o[q];
}

// ---------- pre-pass 2: pack layer-1 weights as MFMA B-fragments ----------
// B-frag lane layout for mfma_f32_16x16x32_f16: col j = lane&15,
// k = 8*(lane>>4) + i  (i = 0..7). Must match the A-side LDS read order
// (feats stored in natural k order, lane reads granule lane>>4) — MFMA is
// k-permutation-invariant as long as A and B use the SAME map.
__global__ __launch_bounds__(256) void pack_bfrags(
    const float* __restrict__ Wd1, const float* __restrict__ Wc1,
    f16* __restrict__ Bd, f16* __restrict__ Bc)
{
    const int idx  = threadIdx.x;          // 0..255, single block
    const int nt   = idx >> 6;             // N-tile 0..3
    const int lane = idx & 63;
    const int j    = nt*16 + (lane & 15);
    const int k0   = (lane >> 4) * 8;
    f16x8 vd, vc;
    #pragma unroll
    for (int i = 0; i < 8; ++i) {
        vd[i] = (f16)Wd1[(k0+i)*64 + j];
        vc[i] = (f16)Wc1[(k0+i)*64 + j];
    }
    *(f16x8*)(Bd + ((size_t)(nt*64+lane))*8) = vd;
    *(f16x8*)(Bc + ((size_t)(nt*64+lane))*8) = vc;
}

// ---------- main fused kernel ----------
// USE_MFMA=true: feats staged to LDS as f16; layer-1 of both MLPs on the
// matrix pipe (4 Mt x 4 Nt x 2 layers = 32 MFMAs/wave); layer-2 via per-lane
// relu*w + 16-lane shfl_xor reduce; sigma/rgb returned to owner threads via LDS.
template<bool USE_MFMA>
__global__ __launch_bounds__(256) __attribute__((amdgpu_waves_per_eu(2, 6)))
void nerf_fused(
    const float* __restrict__ rays_o, const float* __restrict__ rays_d,
    const float* __restrict__ G1, const float* __restrict__ Fg,
    const float* __restrict__ Wd1, const float* __restrict__ bd1,
    const float* __restrict__ Wd2, const float* __restrict__ bd2,
    const float* __restrict__ Wc1, const float* __restrict__ bc1,
    const float* __restrict__ Wc2, const float* __restrict__ bc2,
    const float* __restrict__ Ft,
    const f16* __restrict__ Bd, const f16* __restrict__ Bc,
    float* __restrict__ out)
{
    const float RADIUS = 1.3f;
    const float STEP = 0.0176f;

    const int b    = blockIdx.x;
    const int tid  = threadIdx.x;
    const int lane = tid & 63;
    const int wv   = tid >> 6;

    __shared__ __align__(16) f16 feats_lds[256][32];  // 16 KB
    __shared__ float sig_lds[256];                    // 1 KB
    __shared__ f16   rgb_lds[256][4];                 // 2 KB (r,g,b,pad)
    __shared__ float s_wtot[4];
    __shared__ float s_red[4][4];

    // ---- ray setup ----
    const float ox = rays_o[b*3+0], oy = rays_o[b*3+1], oz = rays_o[b*3+2];
    const float rdx = rays_d[b*3+0], rdy = rays_d[b*3+1], rdz = rays_d[b*3+2];
    const float rn  = sqrtf(rdx*rdx + rdy*rdy + rdz*rdz);
    const float dxn = rdx/rn, dyn = rdy/rn, dzn = rdz/rn;

    // ---- cube intersection ----
    float sd, inv, t1, t2, tmin, tmax;
    sd = (fabsf(dxn) < 1e-9f) ? 1e-9f : dxn; inv = 1.0f/sd;
    t1 = (-RADIUS - ox)*inv; t2 = (RADIUS - ox)*inv;
    tmin = fminf(t1,t2); tmax = fmaxf(t1,t2);
    sd = (fabsf(dyn) < 1e-9f) ? 1e-9f : dyn; inv = 1.0f/sd;
    t1 = (-RADIUS - oy)*inv; t2 = (RADIUS - oy)*inv;
    tmin = fmaxf(tmin, fminf(t1,t2)); tmax = fminf(tmax, fmaxf(t1,t2));
    sd = (fabsf(dzn) < 1e-9f) ? 1e-9f : dzn; inv = 1.0f/sd;
    t1 = (-RADIUS - oz)*inv; t2 = (RADIUS - oz)*inv;
    tmin = fmaxf(tmin, fminf(t1,t2)); tmax = fminf(tmax, fmaxf(t1,t2));

    const float tnear = fmaxf(tmin, 0.0f);
    const bool  hit   = tmax > tnear;
    const float t     = tnear + STEP * (float)tid;
    const bool  mask  = (t < tmax) && hit;

    const bool wave_active = __any(mask);

    float sigma = 0.0f, rr = 0.0f, rg = 0.0f, rb = 0.0f;

    // =========================== gather phase ===========================
    float feats[32];
    if (wave_active) {
        const float invR = 1.0f / RADIUS;
        const float px = (ox + t*dxn) * invR;
        const float py = (oy + t*dyn) * invR;
        const float pz = (oz + t*dzn) * invR;

        float cox = fminf(fmaxf((px+1.0f)*0.5f*127.0f, 0.0f), 127.0f);
        float coy = fminf(fmaxf((py+1.0f)*0.5f*127.0f, 0.0f), 127.0f);
        float coz = fminf(fmaxf((pz+1.0f)*0.5f*127.0f, 0.0f), 127.0f);
        int x0 = (int)floorf(cox); float fx = cox - (float)x0; int x1 = min(x0+1, 127);
        int y0 = (int)floorf(coy); float fy = coy - (float)y0; int y1 = min(y0+1, 127);
        int z0 = (int)floorf(coz); float fz = coz - (float)z0; int z1 = min(z0+1, 127);

        {
            const float wx0 = 1.0f-fx, wx1 = fx;
            const float wy0 = 1.0f-fy, wy1 = fy;
            const float wz0 = 1.0f-fz, wz1 = fz;
            const float w000 = wx0*wy0*wz0, w100 = wx1*wy0*wz0;
            const float w010 = wx0*wy1*wz0, w110 = wx1*wy1*wz0;
            const float w001 = wx0*wy0*wz1, w101 = wx1*wy0*wz1;
            const float w011 = wx0*wy1*wz1, w111 = wx1*wy1*wz1;
            const int i000 = (z0*128 + y0)*128 + x0;
            const int dxo = x1 - x0;
            const int dyo = (y1 - y0)*128;
            const int dzo = (z1 - z0)*16384;
            const int i100 = i000 + dxo,       i010 = i000 + dyo;
            const int i110 = i000 + dyo + dxo, i001 = i000 + dzo;
            const int i101 = i000 + dzo + dxo, i011 = i000 + dzo + dyo;
            const int i111 = i000 + dzo + dyo + dxo;

            float g[3];
            #pragma unroll
            for (int c = 0; c < 3; ++c) {
                const float* gp = G1 + (size_t)c * 2097152;
                g[c] = w000*gp[i000] + w100*gp[i100] + w010*gp[i010] + w110*gp[i110]
                     + w001*gp[i001] + w101*gp[i101] + w011*gp[i011] + w111*gp[i111];
            }

            cox = fminf(fmaxf((g[0]+1.0f)*0.5f*31.0f, 0.0f), 31.0f);
            coy = fminf(fmaxf((g[1]+1.0f)*0.5f*31.0f, 0.0f), 31.0f);
            coz = fminf(fmaxf((g[2]+1.0f)*0.5f*31.0f, 0.0f), 31.0f);
            x0 = (int)floorf(cox); fx = cox - (float)x0; x1 = min(x0+1, 31);
            y0 = (int)floorf(coy); fy = coy - (float)y0; y1 = min(y0+1, 31);
            z0 = (int)floorf(coz); fz = coz - (float)z0; z1 = min(z0+1, 31);
        }

        #pragma unroll
        for (int c = 0; c < 32; ++c) feats[c] = 0.0f;
        {
            const float wx0 = 1.0f-fx, wx1 = fx;
            const float wy0 = 1.0f-fy, wy1 = fy;
            const float wz0 = 1.0f-fz, wz1 = fz;
            const int j000 = (z0*32 + y0)*32 + x0;
            const int dxo = x1 - x0;
            const int dyo = (y1 - y0)*32;
            const int dzo = (z1 - z0)*1024;

            const int   jidx[8] = { j000,           j000+dxo,
                                    j000+dyo,       j000+dyo+dxo,
                                    j000+dzo,       j000+dzo+dxo,
                                    j000+dzo+dyo,   j000+dzo+dyo+dxo };
            const float jwt[8]  = { wx0*wy0*wz0, wx1*wy0*wz0,
                                    wx0*wy1*wz0, wx1*wy1*wz0,
                                    wx0*wy0*wz1, wx1*wy0*wz1,
                                    wx0*wy1*wz1, wx1*wy1*wz1 };

            if (USE_MFMA) {
                #pragma unroll
                for (int corner = 0; corner < 8; ++corner) {
                    const float4* fp = (const float4*)(Ft + (size_t)jidx[corner] * 32);
                    const float w = jwt[corner];
                    #pragma unroll
                    for (int q = 0; q < 8; ++q) {
                        const float4 v = fp[q];
                        feats[4*q+0] += w * v.x;
                        feats[4*q+1] += w * v.y;
                        feats[4*q+2] += w * v.z;
                        feats[4*q+3] += w * v.w;
                    }
                }
            } else {
                #pragma unroll
                for (int corner = 0; corner < 8; ++corner) {
                    const float w = jwt[corner];
                    const int  j  = jidx[corner];
                    #pragma unroll
                    for (int c = 0; c < 32; ++c)
                        feats[c] += w * Fg[(size_t)c * 32768 + j];
                }
            }
        }
    }

    if (USE_MFMA) {
        // ---- stage feats to LDS as f16 (4 x 16B stores) ----
        if (wave_active) {
            #pragma unroll
            for (int gq = 0; gq < 4; ++gq) {
                f16x8 h;
                #pragma unroll
                for (int i = 0; i < 8; ++i) h[i] = (f16)feats[gq*8+i];
                *(f16x8*)&feats_lds[tid][gq*8] = h;
            }
        }
        __syncthreads();

        // ---- MFMA phase: each wave computes its own 64 samples ----
        if (wave_active) {
            const int lane15 = lane & 15;
            const int laneg  = lane >> 4;

            float bias_d[4], bias_c[4], wd2v[4];
            float wc2r[4], wc2g[4], wc2b[4];
            #pragma unroll
            for (int nt = 0; nt < 4; ++nt) {
                const int j = nt*16 + lane15;
                bias_d[nt] = bd1[j];
                bias_c[nt] = bc1[j] + dxn*Wc1[32*64+j] + dyn*Wc1[33*64+j] + dzn*Wc1[34*64+j];
                wd2v[nt]   = Wd2[j];
                wc2r[nt]   = Wc2[j*3+0];
                wc2g[nt]   = Wc2[j*3+1];
                wc2b[nt]   = Wc2[j*3+2];
            }
            f16x8 bdf[4], bcf[4];
            #pragma unroll
            for (int nt = 0; nt < 4; ++nt) {
                bdf[nt] = *(const f16x8*)(Bd + ((size_t)(nt*64+lane))*8);
                bcf[nt] = *(const f16x8*)(Bc + ((size_t)(nt*64+lane))*8);
            }

            #pragma unroll
            for (int mt = 0; mt < 4; ++mt) {
                const int arow = wv*64 + mt*16 + lane15;
                const f16x8 af = *(const f16x8*)&feats_lds[arow][laneg*8];

                f32x4 accd[4], accc[4];
                #pragma unroll
                for (int nt = 0; nt < 4; ++nt) {
                    const float bdv = bias_d[nt], bcv = bias_c[nt];
                    accd[nt] = (f32x4){bdv, bdv, bdv, bdv};
                    accc[nt] = (f32x4){bcv, bcv, bcv, bcv};
                }
                #pragma unroll
                for (int nt = 0; nt < 4; ++nt) {
                    accd[nt] = __builtin_amdgcn_mfma_f32_16x16x32_f16(af, bdf[nt], accd[nt], 0, 0, 0);
                    accc[nt] = __builtin_amdgcn_mfma_f32_16x16x32_f16(af, bcf[nt], accc[nt], 0, 0, 0);
                }

                // layer-2: per-lane partials then 16-lane reduce
                float ss[4] = {0.f,0.f,0.f,0.f};
                float sr[4] = {0.f,0.f,0.f,0.f};
                float sg[4] = {0.f,0.f,0.f,0.f};
                float sb[4] = {0.f,0.f,0.f,0.f};
                #pragma unroll
                for (int nt = 0; nt < 4; ++nt) {
                    #pragma unroll
                    for (int reg = 0; reg < 4; ++reg) {
                        const float hd = fmaxf(accd[nt][reg], 0.0f);
                        ss[reg] += hd * wd2v[nt];
                        const float hc = fmaxf(accc[nt][reg], 0.0f);
                        sr[reg] += hc * wc2r[nt];
                        sg[reg] += hc * wc2g[nt];
                        sb[reg] += hc * wc2b[nt];
                    }
                }
                #pragma unroll
                for (int st = 1; st < 16; st <<= 1) {
                    #pragma unroll
                    for (int reg = 0; reg < 4; ++reg) {
                        ss[reg] += __shfl_xor(ss[reg], st, 64);
                        sr[reg] += __shfl_xor(sr[reg], st, 64);
                        sg[reg] += __shfl_xor(sg[reg], st, 64);
                        sb[reg] += __shfl_xor(sb[reg], st, 64);
                    }
                }
                if (lane15 == 0) {
                    const int base = wv*64 + mt*16 + laneg*4;  // D row = (lane>>4)*4 + reg
                    #pragma unroll
                    for (int reg = 0; reg < 4; ++reg) {
                        sig_lds[base+reg]    = ss[reg];
                        rgb_lds[base+reg][0] = (f16)sr[reg];
                        rgb_lds[base+reg][1] = (f16)sg[reg];
                        rgb_lds[base+reg][2] = (f16)sb[reg];
                    }
                }
            }
        }
        __syncthreads();

        // ---- owner pick-up ----
        {
            const float sv  = sig_lds[tid];
            const float crv = (float)rgb_lds[tid][0] + bc2[0];
            const float cgv = (float)rgb_lds[tid][1] + bc2[1];
            const float cbv = (float)rgb_lds[tid][2] + bc2[2];
            sigma = mask ? (sv + bd2[0]) : 0.0f;
            rr = mask ? 1.0f/(1.0f + expf(-crv)) : 0.0f;
            rg = mask ? 1.0f/(1.0f + expf(-cgv)) : 0.0f;
            rb = mask ? 1.0f/(1.0f + expf(-cbv)) : 0.0f;
        }
    } else {
        // -------- fallback: fp32 per-thread MLP (no workspace needed) --------
        if (wave_active) {
            float sg1 = bd2[0], cr = 0.0f, cg = 0.0f, cb = 0.0f;
            for (int j0 = 0; j0 < 64; j0 += 8) {
                float ad[8], ac[8];
                #pragma unroll
                for (int jj = 0; jj < 8; ++jj) {
                    ad[jj] = bd1[j0+jj];
                    ac[jj] = bc1[j0+jj] + dxn*Wc1[32*64 + j0 + jj]
                                        + dyn*Wc1[33*64 + j0 + jj]
                                        + dzn*Wc1[34*64 + j0 + jj];
                }
                #pragma unroll
                for (int k = 0; k < 32; ++k) {
                    const float fv = feats[k];
                    #pragma unroll
                    for (int jj = 0; jj < 8; ++jj) {
                        ad[jj] += fv * Wd1[k*64 + j0 + jj];
                        ac[jj] += fv * Wc1[k*64 + j0 + jj];
                    }
                }
                #pragma unroll
                for (int jj = 0; jj < 8; ++jj) {
                    sg1 += fmaxf(ad[jj], 0.0f) * Wd2[j0+jj];
                    const float hc = fmaxf(ac[jj], 0.0f);
                    cr += hc * Wc2[(j0+jj)*3 + 0];
                    cg += hc * Wc2[(j0+jj)*3 + 1];
                    cb += hc * Wc2[(j0+jj)*3 + 2];
                }
            }
            cr += bc2[0]; cg += bc2[1]; cb += bc2[2];
            sigma = mask ? sg1 : 0.0f;
            rr = mask ? 1.0f/(1.0f + expf(-cr)) : 0.0f;
            rg = mask ? 1.0f/(1.0f + expf(-cg)) : 0.0f;
            rb = mask ? 1.0f/(1.0f + expf(-cb)) : 0.0f;
        }
    }

    // ---- alpha, exclusive product scan (T_excl), weights ----
    const float alpha = 1.0f - expf(-fmaxf(sigma, 0.0f) * STEP);
    float p = 1.0f - alpha + 1e-10f;

    float scan = p;
    #pragma unroll
    for (int off = 1; off < 64; off <<= 1) {
        const float n = __shfl_up(scan, off, 64);
        if (lane >= off) scan *= n;
    }
    if (lane == 63) s_wtot[wv] = scan;
    __syncthreads();

    float pre = 1.0f;
    #pragma unroll
    for (int q = 0; q < 4; ++q) if (q < wv) pre *= s_wtot[q];
    float excl = __shfl_up(scan, 1, 64);
    if (lane == 0) excl = 1.0f;
    const float Texcl = pre * excl;

    const float w = alpha * Texcl;
    float sw  = w;
    float swr = w * rr, swg = w * rg, swb = w * rb;

    // ---- block reduction ----
    #pragma unroll
    for (int off = 32; off > 0; off >>= 1) {
        sw  += __shfl_down(sw,  off, 64);
        swr += __shfl_down(swr, off, 64);
        swg += __shfl_down(swg, off, 64);
        swb += __shfl_down(swb, off, 64);
    }
    if (lane == 0) {
        s_red[wv][0] = sw;  s_red[wv][1] = swr;
        s_red[wv][2] = swg; s_red[wv][3] = swb;
    }
    __syncthreads();
    if (tid == 0) {
        float W = 0.0f, R = 0.0f, Gc = 0.0f, Bc2_ = 0.0f;
        #pragma unroll
        for (int q = 0; q < 4; ++q) {
            W  += s_red[q][0]; R  += s_red[q][1];
            Gc += s_red[q][2]; Bc2_ += s_red[q][3];
        }
        const float bg = 1.0f - W;
        out[b*3+0] = R  + bg;
        out[b*3+1] = Gc + bg;
        out[b*3+2] = Bc2_ + bg;
    }
}

extern "C" void kernel_launch(void* const* d_in, const int* in_sizes, int n_in,
                              void* d_out, int out_size, void* d_ws, size_t ws_size,
                              hipStream_t stream) {
    const float* rays_o = (const float*)d_in[0];
    const float* rays_d = (const float*)d_in[1];
    const float* G1     = (const float*)d_in[2];
    const float* Fg     = (const float*)d_in[3];
    const float* Wd1    = (const float*)d_in[4];
    const float* bd1    = (const float*)d_in[5];
    const float* Wd2    = (const float*)d_in[6];
    const float* bd2    = (const float*)d_in[7];
    const float* Wc1    = (const float*)d_in[8];
    const float* bc1    = (const float*)d_in[9];
    const float* Wc2    = (const float*)d_in[10];
    const float* bc2    = (const float*)d_in[11];
    float* out = (float*)d_out;

    const int B = in_sizes[0] / 3;   // 2048 rays
    const size_t ft_bytes = (size_t)32768 * 32 * sizeof(float);   // 4 MB
    const size_t bf_bytes = (size_t)4 * 64 * 8 * sizeof(f16);     // 4 KB each

    if (ws_size >= ft_bytes + 2*bf_bytes) {
        float* Ft = (float*)d_ws;
        f16*   Bd = (f16*)((char*)d_ws + ft_bytes);
        f16*   Bc = (f16*)((char*)d_ws + ft_bytes + bf_bytes);
        transpose_F<<<dim3(128), dim3(256), 0, stream>>>(Fg, Ft);
        pack_bfrags<<<dim3(1), dim3(256), 0, stream>>>(Wd1, Wc1, Bd, Bc);
        nerf_fused<true><<<dim3(B), dim3(NSAMP), 0, stream>>>(
            rays_o, rays_d, G1, Fg, Wd1, bd1, Wd2, bd2, Wc1, bc1, Wc2, bc2,
            Ft, Bd, Bc, out);
    } else {
        nerf_fused<false><<<dim3(B), dim3(NSAMP), 0, stream>>>(
            rays_o, rays_d, G1, Fg, Wd1, bd1, Wd2, bd2, Wc1, bc1, Wc2, bc2,
            Fg, (const f16*)d_ws, (const f16*)d_ws, out);
    }
}

// Round 11
// 143.468 us; speedup vs baseline: 1.2083x; 1.0103x over previous
//
#include <hip/hip_runtime.h>
#include <hip/hip_fp16.h>
#include <math.h>

#define NSAMP 256

typedef _Float16 f16;
typedef _Float16 f16x8 __attribute__((ext_vector_type(8)));
typedef float    f32x4 __attribute__((ext_vector_type(4)));

// ---------- pre-pass 1: transpose F [32ch][32768vox] -> Ft [vox][32ch] ----------
__global__ __launch_bounds__(256) void transpose_F(
    const float* __restrict__ Fg, float* __restrict__ Ft)
{
    const int j = blockIdx.x * 256 + threadIdx.x;   // voxel id 0..32767
    float4 o[8];
    #pragma unroll
    for (int q = 0; q < 8; ++q) {
        o[q].x = Fg[(size_t)(4*q+0)*32768 + j];
        o[q].y = Fg[(size_t)(4*q+1)*32768 + j];
        o[q].z = Fg[(size_t)(4*q+2)*32768 + j];
        o[q].w = Fg[(size_t)(4*q+3)*32768 + j];
    }
    float4* dst = (float4*)(Ft + (size_t)j * 32);
    #pragma unroll
    for (int q = 0; q < 8; ++q) dst[q] = o[q];
}

// ---------- pre-pass 1b: interleave G1 [3ch][128^3] -> G1t [128^3][4] ----------
// One float4 per voxel (w = pad): the main kernel's G1 corner gather becomes
// 8 aligned float4 loads (1 cache line each) instead of 24 scalar loads
// across 3 planes 8MB apart.
__global__ __launch_bounds__(256) void transpose_G1(
    const float* __restrict__ G1, float* __restrict__ G1t)
{
    const int v = blockIdx.x * 256 + threadIdx.x;   // 0..2097151
    float4 o;
    o.x = G1[v];
    o.y = G1[2097152 + v];
    o.z = G1[2*2097152 + v];
    o.w = 0.0f;
    ((float4*)G1t)[v] = o;
}

// ---------- pre-pass 2: pack layer-1 weights as MFMA B-fragments ----------
// B-frag lane layout for mfma_f32_16x16x32_f16: col j = lane&15,
// k = 8*(lane>>4) + i (i=0..7). Must match A-side LDS read order.
__global__ __launch_bounds__(256) void pack_bfrags(
    const float* __restrict__ Wd1, const float* __restrict__ Wc1,
    f16* __restrict__ Bd, f16* __restrict__ Bc)
{
    const int idx  = threadIdx.x;          // 0..255, single block
    const int nt   = idx >> 6;             // N-tile 0..3
    const int lane = idx & 63;
    const int j    = nt*16 + (lane & 15);
    const int k0   = (lane >> 4) * 8;
    f16x8 vd, vc;
    #pragma unroll
    for (int i = 0; i < 8; ++i) {
        vd[i] = (f16)Wd1[(k0+i)*64 + j];
        vc[i] = (f16)Wc1[(k0+i)*64 + j];
    }
    *(f16x8*)(Bd + ((size_t)(nt*64+lane))*8) = vd;
    *(f16x8*)(Bc + ((size_t)(nt*64+lane))*8) = vc;
}

// ---------- main fused kernel ----------
// Round-10: (1) G1 gather via interleaved G1t float4 (8 loads vs 24);
// (2) feats_lds rows padded to 40 f16 (80B) so b128 LDS ops spread across
// all 8 bank-groups (fixes the 760K SQ_LDS_BANK_CONFLICT from 64B rows).
template<bool USE_MFMA, bool USE_G1T>
__global__ __launch_bounds__(256) __attribute__((amdgpu_waves_per_eu(2, 6)))
void nerf_fused(
    const float* __restrict__ rays_o, const float* __restrict__ rays_d,
    const float* __restrict__ G1, const float* __restrict__ Fg,
    const float* __restrict__ Wd1, const float* __restrict__ bd1,
    const float* __restrict__ Wd2, const float* __restrict__ bd2,
    const float* __restrict__ Wc1, const float* __restrict__ bc1,
    const float* __restrict__ Wc2, const float* __restrict__ bc2,
    const float* __restrict__ Ft, const float* __restrict__ G1t,
    const f16* __restrict__ Bd, const f16* __restrict__ Bc,
    float* __restrict__ out)
{
    const float RADIUS = 1.3f;
    const float STEP = 0.0176f;

    const int b    = blockIdx.x;
    const int tid  = threadIdx.x;
    const int lane = tid & 63;
    const int wv   = tid >> 6;

    __shared__ __align__(16) f16 feats_lds[256][40];  // 80B rows: bank-spread
    __shared__ float sig_lds[256];
    __shared__ f16   rgb_lds[256][4];
    __shared__ float s_wtot[4];
    __shared__ float s_red[4][4];

    // ---- ray setup ----
    const float ox = rays_o[b*3+0], oy = rays_o[b*3+1], oz = rays_o[b*3+2];
    const float rdx = rays_d[b*3+0], rdy = rays_d[b*3+1], rdz = rays_d[b*3+2];
    const float rn  = sqrtf(rdx*rdx + rdy*rdy + rdz*rdz);
    const float dxn = rdx/rn, dyn = rdy/rn, dzn = rdz/rn;

    // ---- cube intersection ----
    float sd, inv, t1, t2, tmin, tmax;
    sd = (fabsf(dxn) < 1e-9f) ? 1e-9f : dxn; inv = 1.0f/sd;
    t1 = (-RADIUS - ox)*inv; t2 = (RADIUS - ox)*inv;
    tmin = fminf(t1,t2); tmax = fmaxf(t1,t2);
    sd = (fabsf(dyn) < 1e-9f) ? 1e-9f : dyn; inv = 1.0f/sd;
    t1 = (-RADIUS - oy)*inv; t2 = (RADIUS - oy)*inv;
    tmin = fmaxf(tmin, fminf(t1,t2)); tmax = fminf(tmax, fmaxf(t1,t2));
    sd = (fabsf(dzn) < 1e-9f) ? 1e-9f : dzn; inv = 1.0f/sd;
    t1 = (-RADIUS - oz)*inv; t2 = (RADIUS - oz)*inv;
    tmin = fmaxf(tmin, fminf(t1,t2)); tmax = fminf(tmax, fmaxf(t1,t2));

    const float tnear = fmaxf(tmin, 0.0f);
    const bool  hit   = tmax > tnear;
    const float t     = tnear + STEP * (float)tid;
    const bool  mask  = (t < tmax) && hit;

    const bool wave_active = __any(mask);

    float sigma = 0.0f, rr = 0.0f, rg = 0.0f, rb = 0.0f;

    // =========================== gather phase ===========================
    float feats[32];
    if (wave_active) {
        const float invR = 1.0f / RADIUS;
        const float px = (ox + t*dxn) * invR;
        const float py = (oy + t*dyn) * invR;
        const float pz = (oz + t*dzn) * invR;

        float cox = fminf(fmaxf((px+1.0f)*0.5f*127.0f, 0.0f), 127.0f);
        float coy = fminf(fmaxf((py+1.0f)*0.5f*127.0f, 0.0f), 127.0f);
        float coz = fminf(fmaxf((pz+1.0f)*0.5f*127.0f, 0.0f), 127.0f);
        int x0 = (int)floorf(cox); float fx = cox - (float)x0; int x1 = min(x0+1, 127);
        int y0 = (int)floorf(coy); float fy = coy - (float)y0; int y1 = min(y0+1, 127);
        int z0 = (int)floorf(coz); float fz = coz - (float)z0; int z1 = min(z0+1, 127);

        {
            const float wx0 = 1.0f-fx, wx1 = fx;
            const float wy0 = 1.0f-fy, wy1 = fy;
            const float wz0 = 1.0f-fz, wz1 = fz;
            const float w000 = wx0*wy0*wz0, w100 = wx1*wy0*wz0;
            const float w010 = wx0*wy1*wz0, w110 = wx1*wy1*wz0;
            const float w001 = wx0*wy0*wz1, w101 = wx1*wy0*wz1;
            const float w011 = wx0*wy1*wz1, w111 = wx1*wy1*wz1;
            const int i000 = (z0*128 + y0)*128 + x0;
            const int dxo = x1 - x0;
            const int dyo = (y1 - y0)*128;
            const int dzo = (z1 - z0)*16384;
            const int i100 = i000 + dxo,       i010 = i000 + dyo;
            const int i110 = i000 + dyo + dxo, i001 = i000 + dzo;
            const int i101 = i000 + dzo + dxo, i011 = i000 + dzo + dyo;
            const int i111 = i000 + dzo + dyo + dxo;

            float g[3];
            if (USE_G1T) {
                const float4* gp = (const float4*)G1t;
                const float4 v000 = gp[i000], v100 = gp[i100];
                const float4 v010 = gp[i010], v110 = gp[i110];
                const float4 v001 = gp[i001], v101 = gp[i101];
                const float4 v011 = gp[i011], v111 = gp[i111];
                g[0] = w000*v000.x + w100*v100.x + w010*v010.x + w110*v110.x
                     + w001*v001.x + w101*v101.x + w011*v011.x + w111*v111.x;
                g[1] = w000*v000.y + w100*v100.y + w010*v010.y + w110*v110.y
                     + w001*v001.y + w101*v101.y + w011*v011.y + w111*v111.y;
                g[2] = w000*v000.z + w100*v100.z + w010*v010.z + w110*v110.z
                     + w001*v001.z + w101*v101.z + w011*v011.z + w111*v111.z;
            } else {
                #pragma unroll
                for (int c = 0; c < 3; ++c) {
                    const float* gp = G1 + (size_t)c * 2097152;
                    g[c] = w000*gp[i000] + w100*gp[i100] + w010*gp[i010] + w110*gp[i110]
                         + w001*gp[i001] + w101*gp[i101] + w011*gp[i011] + w111*gp[i111];
                }
            }

            cox = fminf(fmaxf((g[0]+1.0f)*0.5f*31.0f, 0.0f), 31.0f);
            coy = fminf(fmaxf((g[1]+1.0f)*0.5f*31.0f, 0.0f), 31.0f);
            coz = fminf(fmaxf((g[2]+1.0f)*0.5f*31.0f, 0.0f), 31.0f);
            x0 = (int)floorf(cox); fx = cox - (float)x0; x1 = min(x0+1, 31);
            y0 = (int)floorf(coy); fy = coy - (float)y0; y1 = min(y0+1, 31);
            z0 = (int)floorf(coz); fz = coz - (float)z0; z1 = min(z0+1, 31);
        }

        #pragma unroll
        for (int c = 0; c < 32; ++c) feats[c] = 0.0f;
        {
            const float wx0 = 1.0f-fx, wx1 = fx;
            const float wy0 = 1.0f-fy, wy1 = fy;
            const float wz0 = 1.0f-fz, wz1 = fz;
            const int j000 = (z0*32 + y0)*32 + x0;
            const int dxo = x1 - x0;
            const int dyo = (y1 - y0)*32;
            const int dzo = (z1 - z0)*1024;

            const int   jidx[8] = { j000,           j000+dxo,
                                    j000+dyo,       j000+dyo+dxo,
                                    j000+dzo,       j000+dzo+dxo,
                                    j000+dzo+dyo,   j000+dzo+dyo+dxo };
            const float jwt[8]  = { wx0*wy0*wz0, wx1*wy0*wz0,
                                    wx0*wy1*wz0, wx1*wy1*wz0,
                                    wx0*wy0*wz1, wx1*wy0*wz1,
                                    wx0*wy1*wz1, wx1*wy1*wz1 };

            if (USE_MFMA) {
                #pragma unroll
                for (int corner = 0; corner < 8; ++corner) {
                    const float4* fp = (const float4*)(Ft + (size_t)jidx[corner] * 32);
                    const float w = jwt[corner];
                    #pragma unroll
                    for (int q = 0; q < 8; ++q) {
                        const float4 v = fp[q];
                        feats[4*q+0] += w * v.x;
                        feats[4*q+1] += w * v.y;
                        feats[4*q+2] += w * v.z;
                        feats[4*q+3] += w * v.w;
                    }
                }
            } else {
                #pragma unroll
                for (int corner = 0; corner < 8; ++corner) {
                    const float w = jwt[corner];
                    const int  j  = jidx[corner];
                    #pragma unroll
                    for (int c = 0; c < 32; ++c)
                        feats[c] += w * Fg[(size_t)c * 32768 + j];
                }
            }
        }
    }

    if (USE_MFMA) {
        // ---- stage feats to LDS as f16 ----
        if (wave_active) {
            #pragma unroll
            for (int gq = 0; gq < 4; ++gq) {
                f16x8 h;
                #pragma unroll
                for (int i = 0; i < 8; ++i) h[i] = (f16)feats[gq*8+i];
                *(f16x8*)&feats_lds[tid][gq*8] = h;
            }
        }
        __syncthreads();

        // ---- MFMA phase: each wave computes its own 64 samples ----
        if (wave_active) {
            const int lane15 = lane & 15;
            const int laneg  = lane >> 4;

            float bias_d[4], bias_c[4], wd2v[4];
            float wc2r[4], wc2g[4], wc2b[4];
            #pragma unroll
            for (int nt = 0; nt < 4; ++nt) {
                const int j = nt*16 + lane15;
                bias_d[nt] = bd1[j];
                bias_c[nt] = bc1[j] + dxn*Wc1[32*64+j] + dyn*Wc1[33*64+j] + dzn*Wc1[34*64+j];
                wd2v[nt]   = Wd2[j];
                wc2r[nt]   = Wc2[j*3+0];
                wc2g[nt]   = Wc2[j*3+1];
                wc2b[nt]   = Wc2[j*3+2];
            }
            f16x8 bdf[4], bcf[4];
            #pragma unroll
            for (int nt = 0; nt < 4; ++nt) {
                bdf[nt] = *(const f16x8*)(Bd + ((size_t)(nt*64+lane))*8);
                bcf[nt] = *(const f16x8*)(Bc + ((size_t)(nt*64+lane))*8);
            }

            #pragma unroll
            for (int mt = 0; mt < 4; ++mt) {
                const int arow = wv*64 + mt*16 + lane15;
                const f16x8 af = *(const f16x8*)&feats_lds[arow][laneg*8];

                f32x4 accd[4], accc[4];
                #pragma unroll
                for (int nt = 0; nt < 4; ++nt) {
                    const float bdv = bias_d[nt], bcv = bias_c[nt];
                    accd[nt] = (f32x4){bdv, bdv, bdv, bdv};
                    accc[nt] = (f32x4){bcv, bcv, bcv, bcv};
                }
                #pragma unroll
                for (int nt = 0; nt < 4; ++nt) {
                    accd[nt] = __builtin_amdgcn_mfma_f32_16x16x32_f16(af, bdf[nt], accd[nt], 0, 0, 0);
                    accc[nt] = __builtin_amdgcn_mfma_f32_16x16x32_f16(af, bcf[nt], accc[nt], 0, 0, 0);
                }

                // layer-2: per-lane partials then 16-lane reduce
                float ss[4] = {0.f,0.f,0.f,0.f};
                float sr[4] = {0.f,0.f,0.f,0.f};
                float sg[4] = {0.f,0.f,0.f,0.f};
                float sb[4] = {0.f,0.f,0.f,0.f};
                #pragma unroll
                for (int nt = 0; nt < 4; ++nt) {
                    #pragma unroll
                    for (int reg = 0; reg < 4; ++reg) {
                        const float hd = fmaxf(accd[nt][reg], 0.0f);
                        ss[reg] += hd * wd2v[nt];
                        const float hc = fmaxf(accc[nt][reg], 0.0f);
                        sr[reg] += hc * wc2r[nt];
                        sg[reg] += hc * wc2g[nt];
                        sb[reg] += hc * wc2b[nt];
                    }
                }
                #pragma unroll
                for (int st = 1; st < 16; st <<= 1) {
                    #pragma unroll
                    for (int reg = 0; reg < 4; ++reg) {
                        ss[reg] += __shfl_xor(ss[reg], st, 64);
                        sr[reg] += __shfl_xor(sr[reg], st, 64);
                        sg[reg] += __shfl_xor(sg[reg], st, 64);
                        sb[reg] += __shfl_xor(sb[reg], st, 64);
                    }
                }
                if (lane15 == 0) {
                    const int base = wv*64 + mt*16 + laneg*4;  // D row = (lane>>4)*4 + reg
                    #pragma unroll
                    for (int reg = 0; reg < 4; ++reg) {
                        sig_lds[base+reg]    = ss[reg];
                        rgb_lds[base+reg][0] = (f16)sr[reg];
                        rgb_lds[base+reg][1] = (f16)sg[reg];
                        rgb_lds[base+reg][2] = (f16)sb[reg];
                    }
                }
            }
        }
        __syncthreads();

        // ---- owner pick-up ----
        {
            const float sv  = sig_lds[tid];
            const float crv = (float)rgb_lds[tid][0] + bc2[0];
            const float cgv = (float)rgb_lds[tid][1] + bc2[1];
            const float cbv = (float)rgb_lds[tid][2] + bc2[2];
            sigma = mask ? (sv + bd2[0]) : 0.0f;
            rr = mask ? 1.0f/(1.0f + expf(-crv)) : 0.0f;
            rg = mask ? 1.0f/(1.0f + expf(-cgv)) : 0.0f;
            rb = mask ? 1.0f/(1.0f + expf(-cbv)) : 0.0f;
        }
    } else {
        // -------- fallback: fp32 per-thread MLP (no workspace needed) --------
        if (wave_active) {
            float sg1 = bd2[0], cr = 0.0f, cg = 0.0f, cb = 0.0f;
            for (int j0 = 0; j0 < 64; j0 += 8) {
                float ad[8], ac[8];
                #pragma unroll
                for (int jj = 0; jj < 8; ++jj) {
                    ad[jj] = bd1[j0+jj];
                    ac[jj] = bc1[j0+jj] + dxn*Wc1[32*64 + j0 + jj]
                                        + dyn*Wc1[33*64 + j0 + jj]
                                        + dzn*Wc1[34*64 + j0 + jj];
                }
                #pragma unroll
                for (int k = 0; k < 32; ++k) {
                    const float fv = feats[k];
                    #pragma unroll
                    for (int jj = 0; jj < 8; ++jj) {
                        ad[jj] += fv * Wd1[k*64 + j0 + jj];
                        ac[jj] += fv * Wc1[k*64 + j0 + jj];
                    }
                }
                #pragma unroll
                for (int jj = 0; jj < 8; ++jj) {
                    sg1 += fmaxf(ad[jj], 0.0f) * Wd2[j0+jj];
                    const float hc = fmaxf(ac[jj], 0.0f);
                    cr += hc * Wc2[(j0+jj)*3 + 0];
                    cg += hc * Wc2[(j0+jj)*3 + 1];
                    cb += hc * Wc2[(j0+jj)*3 + 2];
                }
            }
            cr += bc2[0]; cg += bc2[1]; cb += bc2[2];
            sigma = mask ? sg1 : 0.0f;
            rr = mask ? 1.0f/(1.0f + expf(-cr)) : 0.0f;
            rg = mask ? 1.0f/(1.0f + expf(-cg)) : 0.0f;
            rb = mask ? 1.0f/(1.0f + expf(-cb)) : 0.0f;
        }
    }

    // ---- alpha, exclusive product scan (T_excl), weights ----
    const float alpha = 1.0f - expf(-fmaxf(sigma, 0.0f) * STEP);
    float p = 1.0f - alpha + 1e-10f;

    float scan = p;
    #pragma unroll
    for (int off = 1; off < 64; off <<= 1) {
        const float n = __shfl_up(scan, off, 64);
        if (lane >= off) scan *= n;
    }
    if (lane == 63) s_wtot[wv] = scan;
    __syncthreads();

    float pre = 1.0f;
    #pragma unroll
    for (int q = 0; q < 4; ++q) if (q < wv) pre *= s_wtot[q];
    float excl = __shfl_up(scan, 1, 64);
    if (lane == 0) excl = 1.0f;
    const float Texcl = pre * excl;

    const float w = alpha * Texcl;
    float sw  = w;
    float swr = w * rr, swg = w * rg, swb = w * rb;

    // ---- block reduction ----
    #pragma unroll
    for (int off = 32; off > 0; off >>= 1) {
        sw  += __shfl_down(sw,  off, 64);
        swr += __shfl_down(swr, off, 64);
        swg += __shfl_down(swg, off, 64);
        swb += __shfl_down(swb, off, 64);
    }
    if (lane == 0) {
        s_red[wv][0] = sw;  s_red[wv][1] = swr;
        s_red[wv][2] = swg; s_red[wv][3] = swb;
    }
    __syncthreads();
    if (tid == 0) {
        float W = 0.0f, R = 0.0f, Gc = 0.0f, Bc2_ = 0.0f;
        #pragma unroll
        for (int q = 0; q < 4; ++q) {
            W  += s_red[q][0]; R  += s_red[q][1];
            Gc += s_red[q][2]; Bc2_ += s_red[q][3];
        }
        const float bg = 1.0f - W;
        out[b*3+0] = R  + bg;
        out[b*3+1] = Gc + bg;
        out[b*3+2] = Bc2_ + bg;
    }
}

extern "C" void kernel_launch(void* const* d_in, const int* in_sizes, int n_in,
                              void* d_out, int out_size, void* d_ws, size_t ws_size,
                              hipStream_t stream) {
    const float* rays_o = (const float*)d_in[0];
    const float* rays_d = (const float*)d_in[1];
    const float* G1     = (const float*)d_in[2];
    const float* Fg     = (const float*)d_in[3];
    const float* Wd1    = (const float*)d_in[4];
    const float* bd1    = (const float*)d_in[5];
    const float* Wd2    = (const float*)d_in[6];
    const float* bd2    = (const float*)d_in[7];
    const float* Wc1    = (const float*)d_in[8];
    const float* bc1    = (const float*)d_in[9];
    const float* Wc2    = (const float*)d_in[10];
    const float* bc2    = (const float*)d_in[11];
    float* out = (float*)d_out;

    const int B = in_sizes[0] / 3;   // 2048 rays
    const size_t ft_bytes  = (size_t)32768 * 32 * sizeof(float);    // 4 MB
    const size_t bf_bytes  = (size_t)4 * 64 * 8 * sizeof(f16);      // 4 KB each
    const size_t g1t_bytes = (size_t)2097152 * 4 * sizeof(float);   // 33.5 MB

    if (ws_size >= ft_bytes + 2*bf_bytes + g1t_bytes) {
        float* Ft  = (float*)d_ws;
        f16*   Bd  = (f16*)((char*)d_ws + ft_bytes);
        f16*   Bc  = (f16*)((char*)d_ws + ft_bytes + bf_bytes);
        float* G1t = (float*)((char*)d_ws + ft_bytes + 2*bf_bytes);
        transpose_F<<<dim3(128), dim3(256), 0, stream>>>(Fg, Ft);
        transpose_G1<<<dim3(8192), dim3(256), 0, stream>>>(G1, G1t);
        pack_bfrags<<<dim3(1), dim3(256), 0, stream>>>(Wd1, Wc1, Bd, Bc);
        nerf_fused<true, true><<<dim3(B), dim3(NSAMP), 0, stream>>>(
            rays_o, rays_d, G1, Fg, Wd1, bd1, Wd2, bd2, Wc1, bc1, Wc2, bc2,
            Ft, G1t, Bd, Bc, out);
    } else if (ws_size >= ft_bytes + 2*bf_bytes) {
        float* Ft = (float*)d_ws;
        f16*   Bd = (f16*)((char*)d_ws + ft_bytes);
        f16*   Bc = (f16*)((char*)d_ws + ft_bytes + bf_bytes);
        transpose_F<<<dim3(128), dim3(256), 0, stream>>>(Fg, Ft);
        pack_bfrags<<<dim3(1), dim3(256), 0, stream>>>(Wd1, Wc1, Bd, Bc);
        nerf_fused<true, false><<<dim3(B), dim3(NSAMP), 0, stream>>>(
            rays_o, rays_d, G1, Fg, Wd1, bd1, Wd2, bd2, Wc1, bc1, Wc2, bc2,
            Ft, G1, Bd, Bc, out);
    } else {
        nerf_fused<false, false><<<dim3(B), dim3(NSAMP), 0, stream>>>(
            rays_o, rays_d, G1, Fg, Wd1, bd1, Wd2, bd2, Wc1, bc1, Wc2, bc2,
            Fg, G1, (const f16*)d_ws, (const f16*)d_ws, out);
    }
}